// Round 8
// baseline (655.734 us; speedup 1.0000x reference)
//
#include <hip/hip_runtime.h>
#include <hip/hip_cooperative_groups.h>

#define C_CH 4096
#define D_DIM 128
#define GRID 512
#define BLOCK 256
#define NTHREADS (GRID * BLOCK)

namespace cg = cooperative_groups;

typedef float f32x2 __attribute__((ext_vector_type(2)));

__global__ __launch_bounds__(BLOCK) void fused_pipeline(
        const float* __restrict__ z, const int* __restrict__ y,
        const int* __restrict__ ids, float* __restrict__ out,
        int* cnt, int* offs, int* cursor, int* first, int* order, int B) {
    cg::grid_group grid = cg::this_grid();
    const int tid  = threadIdx.x;
    const int gtid = blockIdx.x * BLOCK + tid;
    const int nquads = B >> 2;
    const int4* ids4 = (const int4*)ids;

    // ---- phase 0: init ----
    if (gtid < C_CH) { cnt[gtid] = 0; first[gtid] = B - 1; }
    grid.sync();

    // ---- phase 1: count + first (global atomics; 16KB targets spread over TCC) ----
    for (int q = gtid; q < nquads; q += NTHREADS) {
        int4 v = ids4[q];
        int row = q << 2;
        atomicAdd(&cnt[v.x], 1); atomicMin(&first[v.x], row + 0);
        atomicAdd(&cnt[v.y], 1); atomicMin(&first[v.y], row + 1);
        atomicAdd(&cnt[v.z], 1); atomicMin(&first[v.z], row + 2);
        atomicAdd(&cnt[v.w], 1); atomicMin(&first[v.w], row + 3);
    }
    for (int i = (nquads << 2) + gtid; i < B; i += NTHREADS) {
        int c = ids[i];
        atomicAdd(&cnt[c], 1); atomicMin(&first[c], i);
    }
    grid.sync();

    // ---- phase 2: exclusive scan of 4096 counts (block 0 only) ----
    if (blockIdx.x == 0) {
        __shared__ int wsum[4];
        int lane = tid & 63, wv = tid >> 6;
        int base = tid * 16;
        int v[16]; int s = 0;
        #pragma unroll
        for (int k = 0; k < 16; ++k) { v[k] = cnt[base + k]; s += v[k]; }
        int inc = s;
        for (int off = 1; off < 64; off <<= 1) {
            int n = __shfl_up(inc, off, 64);
            if (lane >= off) inc += n;
        }
        if (lane == 63) wsum[wv] = inc;
        __syncthreads();
        int wbase = 0;
        for (int i = 0; i < wv; ++i) wbase += wsum[i];
        int run = wbase + (inc - s);
        #pragma unroll
        for (int k = 0; k < 16; ++k) {
            offs[base + k] = run; cursor[base + k] = run; run += v[k];
        }
        if (tid == BLOCK - 1) offs[C_CH] = run;   // == B
    }
    grid.sync();

    // ---- phase 3: scatter rows into channel-sorted order ----
    for (int q = gtid; q < nquads; q += NTHREADS) {
        int4 v = ids4[q];
        int row = q << 2;
        int p0 = atomicAdd(&cursor[v.x], 1);
        int p1 = atomicAdd(&cursor[v.y], 1);
        int p2 = atomicAdd(&cursor[v.z], 1);
        int p3 = atomicAdd(&cursor[v.w], 1);
        __builtin_nontemporal_store(row + 0, &order[p0]);
        __builtin_nontemporal_store(row + 1, &order[p1]);
        __builtin_nontemporal_store(row + 2, &order[p2]);
        __builtin_nontemporal_store(row + 3, &order[p3]);
    }
    for (int i = (nquads << 2) + gtid; i < B; i += NTHREADS) {
        int pos = atomicAdd(&cursor[ids[i]], 1);
        order[pos] = i;
    }
    grid.sync();

    // ---- phase 4: reduce — one wave per channel, 16 rows in flight ----
    const f32x2* z2 = (const f32x2*)z;
    const int lane = tid & 63;
    const int waveGlobal = (blockIdx.x << 2) + (tid >> 6);   // 0..2047
    for (int w = waveGlobal; w < C_CH; w += GRID * (BLOCK / 64)) {
        int beg = offs[w], end = offs[w + 1];
        f32x2 a0 = {0.f,0.f}, a1 = {0.f,0.f}, a2 = {0.f,0.f}, a3 = {0.f,0.f};
        f32x2 a4 = {0.f,0.f}, a5 = {0.f,0.f}, a6 = {0.f,0.f}, a7 = {0.f,0.f};
        if (end > beg) {
            int idx[16];
            #pragma unroll
            for (int k = 0; k < 16; ++k)
                idx[k] = order[min(beg + k, end - 1)];
            for (int r = beg; r < end; r += 16) {
                f32x2 v[16];
                #pragma unroll
                for (int k = 0; k < 16; ++k)
                    v[k] = __builtin_nontemporal_load(&z2[(size_t)idx[k] * 64 + lane]);
                int rn = r + 16;
                if (rn < end) {
                    #pragma unroll
                    for (int k = 0; k < 16; ++k)
                        idx[k] = order[min(rn + k, end - 1)];
                }
                #pragma unroll
                for (int k = 0; k < 16; ++k) {
                    if (r + k < end) {
                        switch (k & 7) {
                            case 0: a0 += v[k]; break;
                            case 1: a1 += v[k]; break;
                            case 2: a2 += v[k]; break;
                            case 3: a3 += v[k]; break;
                            case 4: a4 += v[k]; break;
                            case 5: a5 += v[k]; break;
                            case 6: a6 += v[k]; break;
                            case 7: a7 += v[k]; break;
                        }
                    }
                }
            }
        }
        f32x2 sum = ((a0 + a1) + (a2 + a3)) + ((a4 + a5) + (a6 + a7));
        float inv = 1.f / (float)max(end - beg, 1);
        f32x2 res; res.x = sum.x * inv; res.y = sum.y * inv;
        ((f32x2*)out)[(size_t)w * 64 + lane] = res;
        if (lane == 0) {
            out[(size_t)C_CH * D_DIM + w] = (float)y[min(first[w], B - 1)];
        }
    }
}

extern "C" void kernel_launch(void* const* d_in, const int* in_sizes, int n_in,
                              void* d_out, int out_size, void* d_ws, size_t ws_size,
                              hipStream_t stream) {
    const float* z   = (const float*)d_in[0];
    const int*   y   = (const int*)d_in[1];
    const int*   ids = (const int*)d_in[2];
    float* out = (float*)d_out;
    int B = in_sizes[2];

    // workspace layout (ints): cnt | offs(+pad) | cursor | first | order
    int* cnt    = (int*)d_ws;
    int* offs   = cnt + C_CH;
    int* cursor = offs + C_CH + 4;
    int* first  = cursor + C_CH;
    int* order  = first + C_CH;

    void* args[] = {(void*)&z, (void*)&y, (void*)&ids, (void*)&out,
                    (void*)&cnt, (void*)&offs, (void*)&cursor, (void*)&first,
                    (void*)&order, (void*)&B};
    hipLaunchCooperativeKernel((void*)fused_pipeline, dim3(GRID), dim3(BLOCK),
                               args, 0, stream);
}